// Round 5
// baseline (418.283 us; speedup 1.0000x reference)
//
#include <hip/hip_runtime.h>
#include <hip/hip_cooperative_groups.h>

namespace cg = cooperative_groups;

#define B_ 64
#define N_ 256
#define V_ 2048
#define E_ 1024

typedef __bf16 bf16_t;
typedef bf16_t bf16x8 __attribute__((ext_vector_type(8)));
typedef float f32x4 __attribute__((ext_vector_type(4)));

// ws layout (float units):
#define OFF_LR  16384     // LR [16384*128]
#define OFF_FT  2113536   // F  [2048*64] feats^T (v-major, b-minor)
#define OFF_WB  2637824   // Wb bf16[128*2048]
#define BK 128

__device__ __forceinline__ void gload_lds16(const bf16_t* g, bf16_t* l) {
    __builtin_amdgcn_global_load_lds((const __attribute__((address_space(1))) void*)g,
                                     (__attribute__((address_space(3))) void*)l, 16, 0, 0);
}

// ---------------- single cooperative kernel: prep -> gemm -> kfs -> linbn --
// grid 256 x 256thr, 1 block/CU. XCD swizzle: blk&7 = xcd; blocks of one
// batch share an XCD so the batch's 128KB LR slice stays in its L2 across
// grid.sync. gemm = proven 32x128 tile code run twice (own batch's 64 rows).
// kfs = R1-exact (grid-256 split; T14 prefetch REGRESSED in R4 — vmcnt
// ordering serializes d-phase behind it — do not retry as-was).
__global__ __launch_bounds__(256) void kmega(
    const float* __restrict__ Vmat,
    const float* __restrict__ U1v, const float* __restrict__ U1g, const float* __restrict__ U1b,
    const float* __restrict__ U2v, const float* __restrict__ U2g, const float* __restrict__ U2b,
    const float* __restrict__ Wl, const float* __restrict__ gam, const float* __restrict__ bet,
    float* __restrict__ LR, float* __restrict__ F, bf16_t* __restrict__ Wb,
    float* __restrict__ out)
{
    cg::grid_group grid = cg::this_grid();
    const int blk = blockIdx.x;
    const int t = threadIdx.x;

    __shared__ bf16_t As[32 * BK];       // 8 KB
    __shared__ bf16_t Bs[128 * BK];      // 32 KB
    __shared__ float pr_red[256];
    __shared__ float pr_sc;
    __shared__ float dl[256];
    __shared__ float kred[4][64];
    __shared__ float lbar[64];
    __shared__ float sl[256];
    __shared__ float4 part[256];
    __shared__ float lred[4][4][64];     // total ~53.5 KB

    // XCD-aware work mapping: same-batch blocks share an XCD
    const int xcd = blk & 7, slot = blk >> 3;
    const int batch = xcd * 8 + (slot >> 2);   // 0..63
    const int vcc = slot & 3;                  // 0..3

    // ---- P0: weight-norm fold (blocks 0..127) ----
    if (blk < 128) {
        const int r = blk;
        const float* v = (r < 64) ? (U1v + (size_t)r * V_) : (U2v + (size_t)(r - 64) * V_);
        float ss = 0.f;
        for (int i = t; i < V_; i += 256) { float x = v[i]; ss += x * x; }
        pr_red[t] = ss;
        __syncthreads();
        for (int o = 128; o > 0; o >>= 1) {
            if (t < (unsigned)o) pr_red[t] += pr_red[t + o];
            __syncthreads();
        }
        if (t == 0) {
            float g = (r < 64) ? U1g[r] : U2g[r - 64];
            pr_sc = g * rsqrtf(pr_red[0]);
        }
        __syncthreads();
        const float s = pr_sc;
        const int k = t * 8;
        float4 f0 = *(const float4*)(v + k);
        float4 f1 = *(const float4*)(v + k + 4);
        bf16x8 o;
        o[0] = (bf16_t)(f0.x * s); o[1] = (bf16_t)(f0.y * s);
        o[2] = (bf16_t)(f0.z * s); o[3] = (bf16_t)(f0.w * s);
        o[4] = (bf16_t)(f1.x * s); o[5] = (bf16_t)(f1.y * s);
        o[6] = (bf16_t)(f1.z * s); o[7] = (bf16_t)(f1.w * s);
        *(bf16x8*)(Wb + (size_t)r * V_ + k) = o;
    }
    grid.sync();

    // ---- P1: MFMA gemm, two 32-row tiles of own batch ----
    {
        const int wv = t >> 6, lane = t & 63;
        const int lm = lane & 15, lq = lane >> 4;
        const int n0w = wv * 32;
        const int ar = t >> 3, au = t & 7;
        bf16_t* adst0 = &As[ar * BK + ((au ^ (ar & 15)) * 8)];
        bf16_t* adst1 = &As[ar * BK + (((au + 8) ^ (ar & 15)) * 8)];
        const int rloc = lane >> 4, cc = lane & 15;
        const int r15 = wv * 4 + rloc;
        const bf16_t* bgsrc = Wb + (size_t)r15 * V_ + (cc ^ r15) * 8;
        const int base_m = batch * 256 + vcc * 64;

        for (int tp = 0; tp < 2; ++tp) {
            const int m0 = base_m + tp * 32;
            const float* aptr = Vmat + (size_t)(m0 + ar) * V_ + au * 8;

            f32x4 acc[2][2];
#pragma unroll
            for (int i = 0; i < 2; ++i)
#pragma unroll
                for (int j = 0; j < 2; ++j) acc[i][j] = (f32x4){0.f, 0.f, 0.f, 0.f};

#pragma unroll
            for (int q = 0; q < 8; ++q)
                gload_lds16(bgsrc + (size_t)q * 16 * V_, &Bs[(q * 16 + wv * 4) * BK]);
            float4 ap0 = *(const float4*)(aptr);
            float4 ap1 = *(const float4*)(aptr + 4);
            float4 ap2 = *(const float4*)(aptr + 64);
            float4 ap3 = *(const float4*)(aptr + 68);

            for (int k0 = 0; k0 < V_; k0 += BK) {
                bf16x8 av0, av1;
                av0[0] = (bf16_t)ap0.x; av0[1] = (bf16_t)ap0.y; av0[2] = (bf16_t)ap0.z; av0[3] = (bf16_t)ap0.w;
                av0[4] = (bf16_t)ap1.x; av0[5] = (bf16_t)ap1.y; av0[6] = (bf16_t)ap1.z; av0[7] = (bf16_t)ap1.w;
                av1[0] = (bf16_t)ap2.x; av1[1] = (bf16_t)ap2.y; av1[2] = (bf16_t)ap2.z; av1[3] = (bf16_t)ap2.w;
                av1[4] = (bf16_t)ap3.x; av1[5] = (bf16_t)ap3.y; av1[6] = (bf16_t)ap3.z; av1[7] = (bf16_t)ap3.w;
                *(bf16x8*)adst0 = av0;
                *(bf16x8*)adst1 = av1;
                __syncthreads();  // B DMA + A writes visible

#pragma unroll
                for (int h = 0; h < 2; ++h) {
                    bf16x8 af[2][2], bfr[2][2];
#pragma unroll
                    for (int i = 0; i < 2; ++i)
#pragma unroll
                        for (int kf = 0; kf < 2; ++kf)
                            af[i][kf] = *(bf16x8*)&As[(i * 16 + lm) * BK + ((((h * 2 + kf) * 4 + lq) ^ lm) * 8)];
#pragma unroll
                    for (int j = 0; j < 2; ++j)
#pragma unroll
                        for (int kf = 0; kf < 2; ++kf)
                            bfr[j][kf] = *(bf16x8*)&Bs[(n0w + j * 16 + lm) * BK + ((((h * 2 + kf) * 4 + lq) ^ lm) * 8)];
                    if (h == 1 && k0 + BK < V_) {
                        ap0 = *(const float4*)(aptr + k0 + BK);
                        ap1 = *(const float4*)(aptr + k0 + BK + 4);
                        ap2 = *(const float4*)(aptr + k0 + BK + 64);
                        ap3 = *(const float4*)(aptr + k0 + BK + 68);
                    }
#pragma unroll
                    for (int i = 0; i < 2; ++i)
#pragma unroll
                        for (int j = 0; j < 2; ++j) {
                            acc[i][j] = __builtin_amdgcn_mfma_f32_16x16x32_bf16(af[i][0], bfr[j][0], acc[i][j], 0, 0, 0);
                            acc[i][j] = __builtin_amdgcn_mfma_f32_16x16x32_bf16(af[i][1], bfr[j][1], acc[i][j], 0, 0, 0);
                        }
                }
                __syncthreads();  // done reading As/Bs
                if (k0 + BK < V_) {
#pragma unroll
                    for (int q = 0; q < 8; ++q)
                        gload_lds16(bgsrc + (size_t)q * 16 * V_ + (k0 + BK), &Bs[(q * 16 + wv * 4) * BK]);
                }
            }
            // epilogue: bias + relu
#pragma unroll
            for (int j = 0; j < 2; ++j) {
                const int n = n0w + j * 16 + lm;
                const float bi = (n < 64) ? U1b[n] : U2b[n - 64];
#pragma unroll
                for (int i = 0; i < 2; ++i)
#pragma unroll
                    for (int r = 0; r < 4; ++r) {
                        const int m = m0 + i * 16 + lq * 4 + r;
                        LR[(size_t)m * 128 + n] = fmaxf(acc[i][j][r] + bi, 0.f);
                    }
            }
        }
    }
    grid.sync();

    // ---- P2: fused d/lbar/s + feats (R1-exact) ----
    {
        const int b = batch, vc = vcc;
        const float* Lb = LR + (size_t)b * N_ * 128;
        const float* row = Lb + (size_t)t * 128;
        float dd = 0.f;
#pragma unroll
        for (int k = 0; k < 64; k += 4) {
            float4 l = *(const float4*)(row + k);
            float4 r = *(const float4*)(row + 64 + k);
            dd += l.x * r.x + l.y * r.y + l.z * r.z + l.w * r.w;
        }
        const float dv = rsqrtf(dd + 1e-6f);
        dl[t] = dv;
        __syncthreads();
        const int k = t & 63, g = t >> 6;
        float acc = 0.f;
        for (int n = g; n < N_; n += 4)
            acc += dl[n] * Lb[(size_t)n * 128 + 64 + k];
        kred[g][k] = acc;
        __syncthreads();
        if (t < 64) lbar[t] = kred[0][t] + kred[1][t] + kred[2][t] + kred[3][t];
        __syncthreads();
        float a2 = 0.f;
#pragma unroll 8
        for (int kk = 0; kk < 64; ++kk) a2 += lbar[kk] * row[kk];
        sl[t] = ((float)(N_ + 1) - dv * a2) * (1.0f / (float)N_);
        __syncthreads();
        const int v4 = t & 127, mh = t >> 7;
        const int v = vc * 512 + v4 * 4;
        const float* base = Vmat + (size_t)b * N_ * V_ + (size_t)mh * 128 * V_ + v;
        float4 a = {0.f, 0.f, 0.f, 0.f};
        for (int m = 0; m < 128; m += 16) {
            float4 x[16];
#pragma unroll
            for (int u = 0; u < 16; ++u) x[u] = *(const float4*)(base + (size_t)(m + u) * V_);
#pragma unroll
            for (int u = 0; u < 16; ++u) {
                float sv = sl[mh * 128 + m + u];
                a.x += sv * x[u].x; a.y += sv * x[u].y;
                a.z += sv * x[u].z; a.w += sv * x[u].w;
            }
        }
        part[t] = a;
        __syncthreads();
        if (mh == 0) {
            float4 p = part[t + 128];
            a = part[t];
            a.x += p.x; a.y += p.y; a.z += p.z; a.w += p.w;
            F[(size_t)(v + 0) * 64 + b] = a.x;
            F[(size_t)(v + 1) * 64 + b] = a.y;
            F[(size_t)(v + 2) * 64 + b] = a.z;
            F[(size_t)(v + 3) * 64 + b] = a.w;
        }
    }
    grid.sync();

    // ---- P3: linear + BatchNorm (256 thr: 4 e-rows x 4 k-slices of 512) ----
    {
        const int e0 = blk * 4;
        const int b = t & 63, g4 = t >> 6;
        const float* w0 = Wl + (size_t)(e0 + 0) * V_ + g4 * 512;
        const float* w1 = Wl + (size_t)(e0 + 1) * V_ + g4 * 512;
        const float* w2 = Wl + (size_t)(e0 + 2) * V_ + g4 * 512;
        const float* w3 = Wl + (size_t)(e0 + 3) * V_ + g4 * 512;
        const float* f0 = F + (size_t)g4 * 512 * 64 + b;
        float a0 = 0.f, a1 = 0.f, a2 = 0.f, a3 = 0.f;
#pragma unroll 4
        for (int kk = 0; kk < 512; ++kk) {
            float fv = f0[(size_t)kk * 64];
            a0 += fv * w0[kk]; a1 += fv * w1[kk]; a2 += fv * w2[kk]; a3 += fv * w3[kk];
        }
        lred[g4][0][b] = a0; lred[g4][1][b] = a1; lred[g4][2][b] = a2; lred[g4][3][b] = a3;
        __syncthreads();
        const int e = t >> 6;
        float vv = lred[0][e][b] + lred[1][e][b] + lred[2][e][b] + lred[3][e][b];
        float sum = vv;
#pragma unroll
        for (int o = 1; o < 64; o <<= 1) sum += __shfl_xor(sum, o, 64);
        float mu = sum * (1.f / 64.f);
        float dvv = vv - mu;
        float q = dvv * dvv;
#pragma unroll
        for (int o = 1; o < 64; o <<= 1) q += __shfl_xor(q, o, 64);
        float inv = rsqrtf(q * (1.f / 64.f) + 1e-5f);
        lred[0][e][b] = gam[e0 + e] * dvv * inv + bet[e0 + e];
        __syncthreads();
        const int b2 = t >> 2, j = t & 3;
        out[(size_t)b2 * E_ + e0 + j] = lred[0][j][b2];
    }
}

extern "C" void kernel_launch(void* const* d_in, const int* in_sizes, int n_in,
                              void* d_out, int out_size, void* d_ws, size_t ws_size,
                              hipStream_t stream) {
    const float* Vmat = (const float*)d_in[0];
    const float* U1v  = (const float*)d_in[1];
    const float* U1g  = (const float*)d_in[2];
    const float* U1b  = (const float*)d_in[3];
    const float* U2v  = (const float*)d_in[4];
    const float* U2g  = (const float*)d_in[5];
    const float* U2b  = (const float*)d_in[6];
    const float* Wl   = (const float*)d_in[7];
    // d_in[8] = b_lin: unused (cancels in BatchNorm)
    const float* gam  = (const float*)d_in[9];
    const float* bet  = (const float*)d_in[10];

    float*  ws   = (float*)d_ws;
    float*  LRp  = ws + OFF_LR;
    float*  Fp   = ws + OFF_FT;
    bf16_t* Wbp  = (bf16_t*)(ws + OFF_WB);
    float*  outp = (float*)d_out;

    void* args[] = {(void*)&Vmat, (void*)&U1v, (void*)&U1g, (void*)&U1b,
                    (void*)&U2v, (void*)&U2g, (void*)&U2b,
                    (void*)&Wl, (void*)&gam, (void*)&bet,
                    (void*)&LRp, (void*)&Fp, (void*)&Wbp, (void*)&outp};
    hipLaunchCooperativeKernel((void*)kmega, dim3(256), dim3(256), args, 0, stream);
}

// Round 6
// 277.172 us; speedup vs baseline: 1.5091x; 1.5091x over previous
//
#include <hip/hip_runtime.h>

#define B_ 64
#define N_ 256
#define V_ 2048
#define E_ 1024
#define MROWS 16384  // B_*N_

typedef __bf16 bf16_t;
typedef bf16_t bf16x8 __attribute__((ext_vector_type(8)));
typedef float f32x4 __attribute__((ext_vector_type(4)));

// ws layout (float units):
#define OFF_LR  16384     // LR     [16384*128]
#define OFF_FT  2113536   // F [2048*64] final feats^T (v-major, b-minor)
#define OFF_WB  2637824   // Wb bf16[128*2048] (= 131072 floats)

__device__ __forceinline__ void gload_lds16(const bf16_t* g, bf16_t* l) {
    __builtin_amdgcn_global_load_lds((const __attribute__((address_space(1))) void*)g,
                                     (__attribute__((address_space(3))) void*)l, 16, 0, 0);
}

// ---------------- kernel 1: weight-norm scale folded into bf16 weights ----
__global__ void kprep(const float* __restrict__ U1v, const float* __restrict__ U1g,
                      const float* __restrict__ U2v, const float* __restrict__ U2g,
                      bf16_t* __restrict__ Wb) {
    __shared__ float red[256];
    __shared__ float sc;
    const int r = blockIdx.x;  // 0..127
    const float* v = (r < 64) ? (U1v + (size_t)r * V_) : (U2v + (size_t)(r - 64) * V_);
    float ss = 0.f;
    for (int i = threadIdx.x; i < V_; i += 256) { float x = v[i]; ss += x * x; }
    red[threadIdx.x] = ss;
    __syncthreads();
    for (int o = 128; o > 0; o >>= 1) {
        if (threadIdx.x < (unsigned)o) red[threadIdx.x] += red[threadIdx.x + o];
        __syncthreads();
    }
    if (threadIdx.x == 0) {
        float g = (r < 64) ? U1g[r] : U2g[r - 64];
        sc = g * rsqrtf(red[0]);
    }
    __syncthreads();
    const float s = sc;
    const int k = threadIdx.x * 8;
    float4 f0 = *(const float4*)(v + k);
    float4 f1 = *(const float4*)(v + k + 4);
    bf16x8 o;
    o[0] = (bf16_t)(f0.x * s); o[1] = (bf16_t)(f0.y * s);
    o[2] = (bf16_t)(f0.z * s); o[3] = (bf16_t)(f0.w * s);
    o[4] = (bf16_t)(f1.x * s); o[5] = (bf16_t)(f1.y * s);
    o[6] = (bf16_t)(f1.z * s); o[7] = (bf16_t)(f1.w * s);
    *(bf16x8*)(Wb + (size_t)r * V_ + k) = o;
}

// ---------------- kernel 2: MFMA bf16 projections, BK=128 ------------------
// LR[16384x128] = relu(Vmat * Wb^T + bias). Tile 32m x 128n, grid 512.
// B via global_load_lds dwordx4 (dist 1), A fp32 reg-prefetch + in-reg bf16
// convert, XOR-swizzled LDS (mod 16), 2 barriers per 128-K iter (16 iters).
// NOTE: dbuf/no-barrier/split-K/dist-2 all regress (R4-R7) — do not retry.
// R5: 1-block/CU cooperative mega-kernel regressed (233us, occ 11.7%) —
// whole pipeline is LATENCY-bound; FETCH 146MB confirms Vmat 2nd read = L3.
#define BK 128
__global__ __launch_bounds__(256) void gemm_lr(
    const float* __restrict__ V, const bf16_t* __restrict__ Wb,
    const float* __restrict__ U1b, const float* __restrict__ U2b,
    float* __restrict__ LR) {
    __shared__ bf16_t As[32 * BK];    // 8 KB
    __shared__ bf16_t Bs[128 * BK];   // 32 KB
    const int t = threadIdx.x;
    const int m0 = blockIdx.x * 32;
    const int wv = t >> 6, lane = t & 63;
    const int lm = lane & 15, lq = lane >> 4;
    const int n0w = wv * 32;

    // A staging: thread -> (row ar 0..31, chunks au and au+8 of 16), XOR mod16
    const int ar = t >> 3, au = t & 7;
    const float* aptr = V + (size_t)(m0 + ar) * V_ + au * 8;
    bf16_t* adst0 = &As[ar * BK + ((au ^ (ar & 15)) * 8)];
    bf16_t* adst1 = &As[ar * BK + (((au + 8) ^ (ar & 15)) * 8)];

    // B DMA: instr covers 4 rows (64 lanes x 16B = 1KB); lane -> row
    // r15 = wv*4 + (lane>>4), chunk cc = lane&15, global-side XOR swizzle.
    const int rloc = lane >> 4, cc = lane & 15;
    const int r15 = wv * 4 + rloc;
    const bf16_t* bgsrc = Wb + (size_t)r15 * V_ + (cc ^ r15) * 8;

    f32x4 acc[2][2];
#pragma unroll
    for (int i = 0; i < 2; ++i)
#pragma unroll
        for (int j = 0; j < 2; ++j) acc[i][j] = (f32x4){0.f, 0.f, 0.f, 0.f};

    // prologue: B DMA for k0=0 (8 instrs cover 128 rows), A regs for k0=0
#pragma unroll
    for (int q = 0; q < 8; ++q)
        gload_lds16(bgsrc + (size_t)q * 16 * V_, &Bs[(q * 16 + wv * 4) * BK]);
    float4 ap0 = *(const float4*)(aptr);
    float4 ap1 = *(const float4*)(aptr + 4);
    float4 ap2 = *(const float4*)(aptr + 64);
    float4 ap3 = *(const float4*)(aptr + 68);

    for (int k0 = 0; k0 < V_; k0 += BK) {
        bf16x8 av0, av1;
        av0[0] = (bf16_t)ap0.x; av0[1] = (bf16_t)ap0.y; av0[2] = (bf16_t)ap0.z; av0[3] = (bf16_t)ap0.w;
        av0[4] = (bf16_t)ap1.x; av0[5] = (bf16_t)ap1.y; av0[6] = (bf16_t)ap1.z; av0[7] = (bf16_t)ap1.w;
        av1[0] = (bf16_t)ap2.x; av1[1] = (bf16_t)ap2.y; av1[2] = (bf16_t)ap2.z; av1[3] = (bf16_t)ap2.w;
        av1[4] = (bf16_t)ap3.x; av1[5] = (bf16_t)ap3.y; av1[6] = (bf16_t)ap3.z; av1[7] = (bf16_t)ap3.w;
        *(bf16x8*)adst0 = av0;
        *(bf16x8*)adst1 = av1;
        __syncthreads();  // B DMA + A writes visible

#pragma unroll
        for (int h = 0; h < 2; ++h) {
            bf16x8 af[2][2], bfr[2][2];
#pragma unroll
            for (int i = 0; i < 2; ++i)
#pragma unroll
                for (int kf = 0; kf < 2; ++kf)
                    af[i][kf] = *(bf16x8*)&As[(i * 16 + lm) * BK + ((((h * 2 + kf) * 4 + lq) ^ lm) * 8)];
#pragma unroll
            for (int j = 0; j < 2; ++j)
#pragma unroll
                for (int kf = 0; kf < 2; ++kf)
                    bfr[j][kf] = *(bf16x8*)&Bs[(n0w + j * 16 + lm) * BK + ((((h * 2 + kf) * 4 + lq) ^ lm) * 8)];
            if (h == 1 && k0 + BK < V_) {  // A reg prefetch for next iter
                ap0 = *(const float4*)(aptr + k0 + BK);
                ap1 = *(const float4*)(aptr + k0 + BK + 4);
                ap2 = *(const float4*)(aptr + k0 + BK + 64);
                ap3 = *(const float4*)(aptr + k0 + BK + 68);
            }
#pragma unroll
            for (int i = 0; i < 2; ++i)
#pragma unroll
                for (int j = 0; j < 2; ++j) {
                    acc[i][j] = __builtin_amdgcn_mfma_f32_16x16x32_bf16(af[i][0], bfr[j][0], acc[i][j], 0, 0, 0);
                    acc[i][j] = __builtin_amdgcn_mfma_f32_16x16x32_bf16(af[i][1], bfr[j][1], acc[i][j], 0, 0, 0);
                }
        }
        __syncthreads();  // done reading As/Bs
        if (k0 + BK < V_) {
#pragma unroll
            for (int q = 0; q < 8; ++q)
                gload_lds16(bgsrc + (size_t)q * 16 * V_ + (k0 + BK), &Bs[(q * 16 + wv * 4) * BK]);
        }
    }
    // epilogue: bias + relu. C/D: n = lane&15 (+16j), m = lq*4 + reg (+16i)
#pragma unroll
    for (int j = 0; j < 2; ++j) {
        const int n = n0w + j * 16 + lm;
        const float bi = (n < 64) ? U1b[n] : U2b[n - 64];
#pragma unroll
        for (int i = 0; i < 2; ++i)
#pragma unroll
            for (int r = 0; r < 4; ++r) {
                const int m = m0 + i * 16 + lq * 4 + r;
                LR[(size_t)m * 128 + n] = fmaxf(acc[i][j][r] + bi, 0.f);
            }
    }
}

// ---------------- kernel 3: fused d/lbar/s + feats, 1024 threads -----------
// grid 256 = b(64) x vc(4) — same split as measured-best R1 (4x s-redundancy;
// 8-way split regressed, R3). R5 counters showed the pipeline is latency-
// bound at ~1 wave/SIMD, so block size 256 -> 1024: 16 waves/CU (4/SIMD) for
// the Vmat-streaming feats phase. d/s chain stays on t<256; lbar widened to
// 16 k-groups. T14-style same-wave prefetch regressed (R4, vmcnt order) —
// here extra WAVES provide the latency cover instead.
__global__ __launch_bounds__(1024) void kfs(const float* __restrict__ LR,
                                            const float* __restrict__ Vmat,
                                            float* __restrict__ F) {
    const int b = blockIdx.x >> 2, vc = blockIdx.x & 3;
    const float* Lb = LR + (size_t)b * N_ * 128;
    __shared__ float dl[256];
    __shared__ float kred[16][64];
    __shared__ float lbar[64];
    __shared__ float sl[256];
    __shared__ float4 part[1024];
    const int t = threadIdx.x;

    // d: per-row dot of right(cols 0..63) and left(cols 64..127), t<256
    const float* row = Lb + (size_t)(t & 255) * 128;
    if (t < 256) {
        float dd = 0.f;
#pragma unroll
        for (int k = 0; k < 64; k += 4) {
            float4 l = *(const float4*)(row + k);
            float4 r = *(const float4*)(row + 64 + k);
            dd += l.x * r.x + l.y * r.y + l.z * r.z + l.w * r.w;
        }
        dl[t] = rsqrtf(dd + 1e-6f);
    }
    __syncthreads();
    // lbar[k] = sum_n dl[n] * left[n][k]; 16 n-groups x 64 k
    {
        const int k = t & 63, g = t >> 6;
        float acc = 0.f;
        for (int n = g; n < N_; n += 16)
            acc += dl[n] * Lb[(size_t)n * 128 + 64 + k];
        kred[g][k] = acc;
    }
    __syncthreads();
    if (t < 64) {
        float v = 0.f;
#pragma unroll
        for (int g = 0; g < 16; ++g) v += kred[g][t];
        lbar[t] = v;
    }
    __syncthreads();
    // s[m] = ((N+1) - d_m * (lbar . right_m)) / N, t<256
    if (t < 256) {
        float a2 = 0.f;
#pragma unroll 8
        for (int kk = 0; kk < 64; ++kk) a2 += lbar[kk] * row[kk];
        sl[t] = ((float)(N_ + 1) - dl[t] * a2) * (1.0f / (float)N_);
    }
    __syncthreads();
    // feats chunk: thread (v4 = t&127, mh = t>>7 in 0..7) covers 32 m-rows
    const int v4 = t & 127, mh = t >> 7;
    const int v = vc * 512 + v4 * 4;
    const float* base = Vmat + (size_t)b * N_ * V_ + (size_t)mh * 32 * V_ + v;
    float4 a = {0.f, 0.f, 0.f, 0.f};
#pragma unroll
    for (int m = 0; m < 32; m += 16) {
        float4 x[16];
#pragma unroll
        for (int u = 0; u < 16; ++u) x[u] = *(const float4*)(base + (size_t)(m + u) * V_);
#pragma unroll
        for (int u = 0; u < 16; ++u) {
            float sv = sl[mh * 32 + m + u];
            a.x += sv * x[u].x; a.y += sv * x[u].y;
            a.z += sv * x[u].z; a.w += sv * x[u].w;
        }
    }
    part[t] = a;
    __syncthreads();
    if (t < 128) {
        a = part[t];
#pragma unroll
        for (int g = 1; g < 8; ++g) {
            float4 p = part[t + g * 128];
            a.x += p.x; a.y += p.y; a.z += p.z; a.w += p.w;
        }
        F[(size_t)(v + 0) * 64 + b] = a.x;
        F[(size_t)(v + 1) * 64 + b] = a.y;
        F[(size_t)(v + 2) * 64 + b] = a.z;
        F[(size_t)(v + 3) * 64 + b] = a.w;
    }
}

// ---------------- kernel 4: fused linear + BatchNorm (512 thr, 8-way K) ---
// single F buffer (0.5MB L2/block). (b_lin dropped: cancels in BatchNorm)
__global__ __launch_bounds__(512) void klinbn(const float* __restrict__ F,
                                              const float* __restrict__ Wl,
                                              const float* __restrict__ gamma,
                                              const float* __restrict__ beta,
                                              float* __restrict__ out) {
    __shared__ float red[8][4][64];
    const int e0 = blockIdx.x * 4;
    const int t = threadIdx.x, b = t & 63, g = t >> 6;  // g: 0..7 k-slices
    const float* w0 = Wl + (size_t)(e0 + 0) * V_ + g * 256;
    const float* w1 = Wl + (size_t)(e0 + 1) * V_ + g * 256;
    const float* w2 = Wl + (size_t)(e0 + 2) * V_ + g * 256;
    const float* w3 = Wl + (size_t)(e0 + 3) * V_ + g * 256;
    const float* f0 = F + (size_t)g * 256 * 64 + b;
    float a0 = 0.f, a1 = 0.f, a2 = 0.f, a3 = 0.f;
#pragma unroll 4
    for (int k = 0; k < 256; ++k) {
        float fv = f0[(size_t)k * 64];
        a0 += fv * w0[k]; a1 += fv * w1[k]; a2 += fv * w2[k]; a3 += fv * w3[k];
    }
    red[g][0][b] = a0; red[g][1][b] = a1; red[g][2][b] = a2; red[g][3][b] = a3;
    __syncthreads();
    if (t < 256) {
        const int e = t >> 6;  // wave e owns e-row e0+e across lanes b
        float v = 0.f;
#pragma unroll
        for (int gg = 0; gg < 8; ++gg) v += red[gg][e][b];
        float sum = v;
#pragma unroll
        for (int o = 1; o < 64; o <<= 1) sum += __shfl_xor(sum, o, 64);
        float mu = sum * (1.f / 64.f);
        float dvv = v - mu;
        float q = dvv * dvv;
#pragma unroll
        for (int o = 1; o < 64; o <<= 1) q += __shfl_xor(q, o, 64);
        float inv = rsqrtf(q * (1.f / 64.f) + 1e-5f);
        red[0][e][b] = gamma[e0 + e] * dvv * inv + beta[e0 + e];
    }
    __syncthreads();
    if (t < 256) {
        const int b2 = t >> 2, j = t & 3;
        out[(size_t)b2 * E_ + e0 + j] = red[0][j][b2];
    }
}

extern "C" void kernel_launch(void* const* d_in, const int* in_sizes, int n_in,
                              void* d_out, int out_size, void* d_ws, size_t ws_size,
                              hipStream_t stream) {
    const float* Vmat = (const float*)d_in[0];
    const float* U1v  = (const float*)d_in[1];
    const float* U1g  = (const float*)d_in[2];
    const float* U1b  = (const float*)d_in[3];
    const float* U2v  = (const float*)d_in[4];
    const float* U2g  = (const float*)d_in[5];
    const float* U2b  = (const float*)d_in[6];
    const float* Wl   = (const float*)d_in[7];
    // d_in[8] = b_lin: unused (cancels in BatchNorm)
    const float* gam  = (const float*)d_in[9];
    const float* bet  = (const float*)d_in[10];

    float*  ws     = (float*)d_ws;
    float*  LR     = ws + OFF_LR;
    float*  F      = ws + OFF_FT;
    bf16_t* Wb     = (bf16_t*)(ws + OFF_WB);

    kprep  <<<128, 256, 0, stream>>>(U1v, U1g, U2v, U2g, Wb);
    gemm_lr<<<MROWS / 32, 256, 0, stream>>>(Vmat, Wb, U1b, U2b, LR);
    kfs    <<<B_ * 4, 1024, 0, stream>>>(LR, Vmat, F);
    klinbn <<<E_ / 4, 512, 0, stream>>>(F, Wl, gam, bet, (float*)d_out);
}

// Round 7
// 271.947 us; speedup vs baseline: 1.5381x; 1.0192x over previous
//
#include <hip/hip_runtime.h>

#define B_ 64
#define N_ 256
#define V_ 2048
#define E_ 1024
#define MROWS 16384  // B_*N_

typedef __bf16 bf16_t;
typedef bf16_t bf16x8 __attribute__((ext_vector_type(8)));
typedef float f32x4 __attribute__((ext_vector_type(4)));

// ws layout (float units):
#define OFF_S   0         // dvec   [16384] rsqrt diag, written by gemm_lr
#define OFF_LR  16384     // LR     [16384*128]
#define OFF_FT  2113536   // F [2048*64] final feats^T (v-major, b-minor)
#define OFF_WB  2637824   // Wb bf16[128*2048] (= 131072 floats)

__device__ __forceinline__ void gload_lds16(const bf16_t* g, bf16_t* l) {
    __builtin_amdgcn_global_load_lds((const __attribute__((address_space(1))) void*)g,
                                     (__attribute__((address_space(3))) void*)l, 16, 0, 0);
}

// ---------------- kernel 1: weight-norm scale folded into bf16 weights ----
__global__ void kprep(const float* __restrict__ U1v, const float* __restrict__ U1g,
                      const float* __restrict__ U2v, const float* __restrict__ U2g,
                      bf16_t* __restrict__ Wb) {
    __shared__ float red[256];
    __shared__ float sc;
    const int r = blockIdx.x;  // 0..127
    const float* v = (r < 64) ? (U1v + (size_t)r * V_) : (U2v + (size_t)(r - 64) * V_);
    float ss = 0.f;
    for (int i = threadIdx.x; i < V_; i += 256) { float x = v[i]; ss += x * x; }
    red[threadIdx.x] = ss;
    __syncthreads();
    for (int o = 128; o > 0; o >>= 1) {
        if (threadIdx.x < (unsigned)o) red[threadIdx.x] += red[threadIdx.x + o];
        __syncthreads();
    }
    if (threadIdx.x == 0) {
        float g = (r < 64) ? U1g[r] : U2g[r - 64];
        sc = g * rsqrtf(red[0]);
    }
    __syncthreads();
    const float s = sc;
    const int k = threadIdx.x * 8;
    float4 f0 = *(const float4*)(v + k);
    float4 f1 = *(const float4*)(v + k + 4);
    bf16x8 o;
    o[0] = (bf16_t)(f0.x * s); o[1] = (bf16_t)(f0.y * s);
    o[2] = (bf16_t)(f0.z * s); o[3] = (bf16_t)(f0.w * s);
    o[4] = (bf16_t)(f1.x * s); o[5] = (bf16_t)(f1.y * s);
    o[6] = (bf16_t)(f1.z * s); o[7] = (bf16_t)(f1.w * s);
    *(bf16x8*)(Wb + (size_t)r * V_ + k) = o;
}

// ---------------- kernel 2: MFMA bf16 projections, BK=128 ------------------
// LR[16384x128] = relu(Vmat * Wb^T + bias). Tile 32m x 128n, grid 512.
// B via global_load_lds dwordx4 (dist 1), A fp32 reg-prefetch + in-reg bf16
// convert, XOR-swizzled LDS (mod 16), 2 barriers per 128-K iter (16 iters).
// NOTE: dbuf/no-barrier/split-K/dist-2 all regress (R4-R7) — do not retry.
// R5: 1-block/CU cooperative mega regressed (occ 11.7%) — latency-bound.
// R7: epilogue additionally computes dvec[m] = rsqrt(right_m . left_m)
// (full 128-col row is resident in this block) so kfs skips its d-phase.
#define BK 128
__global__ __launch_bounds__(256) void gemm_lr(
    const float* __restrict__ V, const bf16_t* __restrict__ Wb,
    const float* __restrict__ U1b, const float* __restrict__ U2b,
    float* __restrict__ LR, float* __restrict__ dvec) {
    __shared__ bf16_t As[32 * BK];    // 8 KB
    __shared__ bf16_t Bs[128 * BK];   // 32 KB
    __shared__ float Cs[32][132];     // 16.9 KB, epilogue tile (pad vs banks)
    const int t = threadIdx.x;
    const int m0 = blockIdx.x * 32;
    const int wv = t >> 6, lane = t & 63;
    const int lm = lane & 15, lq = lane >> 4;
    const int n0w = wv * 32;

    // A staging: thread -> (row ar 0..31, chunks au and au+8 of 16), XOR mod16
    const int ar = t >> 3, au = t & 7;
    const float* aptr = V + (size_t)(m0 + ar) * V_ + au * 8;
    bf16_t* adst0 = &As[ar * BK + ((au ^ (ar & 15)) * 8)];
    bf16_t* adst1 = &As[ar * BK + (((au + 8) ^ (ar & 15)) * 8)];

    // B DMA: instr covers 4 rows (64 lanes x 16B = 1KB); lane -> row
    // r15 = wv*4 + (lane>>4), chunk cc = lane&15, global-side XOR swizzle.
    const int rloc = lane >> 4, cc = lane & 15;
    const int r15 = wv * 4 + rloc;
    const bf16_t* bgsrc = Wb + (size_t)r15 * V_ + (cc ^ r15) * 8;

    f32x4 acc[2][2];
#pragma unroll
    for (int i = 0; i < 2; ++i)
#pragma unroll
        for (int j = 0; j < 2; ++j) acc[i][j] = (f32x4){0.f, 0.f, 0.f, 0.f};

    // prologue: B DMA for k0=0 (8 instrs cover 128 rows), A regs for k0=0
#pragma unroll
    for (int q = 0; q < 8; ++q)
        gload_lds16(bgsrc + (size_t)q * 16 * V_, &Bs[(q * 16 + wv * 4) * BK]);
    float4 ap0 = *(const float4*)(aptr);
    float4 ap1 = *(const float4*)(aptr + 4);
    float4 ap2 = *(const float4*)(aptr + 64);
    float4 ap3 = *(const float4*)(aptr + 68);

    for (int k0 = 0; k0 < V_; k0 += BK) {
        bf16x8 av0, av1;
        av0[0] = (bf16_t)ap0.x; av0[1] = (bf16_t)ap0.y; av0[2] = (bf16_t)ap0.z; av0[3] = (bf16_t)ap0.w;
        av0[4] = (bf16_t)ap1.x; av0[5] = (bf16_t)ap1.y; av0[6] = (bf16_t)ap1.z; av0[7] = (bf16_t)ap1.w;
        av1[0] = (bf16_t)ap2.x; av1[1] = (bf16_t)ap2.y; av1[2] = (bf16_t)ap2.z; av1[3] = (bf16_t)ap2.w;
        av1[4] = (bf16_t)ap3.x; av1[5] = (bf16_t)ap3.y; av1[6] = (bf16_t)ap3.z; av1[7] = (bf16_t)ap3.w;
        *(bf16x8*)adst0 = av0;
        *(bf16x8*)adst1 = av1;
        __syncthreads();  // B DMA + A writes visible

#pragma unroll
        for (int h = 0; h < 2; ++h) {
            bf16x8 af[2][2], bfr[2][2];
#pragma unroll
            for (int i = 0; i < 2; ++i)
#pragma unroll
                for (int kf = 0; kf < 2; ++kf)
                    af[i][kf] = *(bf16x8*)&As[(i * 16 + lm) * BK + ((((h * 2 + kf) * 4 + lq) ^ lm) * 8)];
#pragma unroll
            for (int j = 0; j < 2; ++j)
#pragma unroll
                for (int kf = 0; kf < 2; ++kf)
                    bfr[j][kf] = *(bf16x8*)&Bs[(n0w + j * 16 + lm) * BK + ((((h * 2 + kf) * 4 + lq) ^ lm) * 8)];
            if (h == 1 && k0 + BK < V_) {  // A reg prefetch for next iter
                ap0 = *(const float4*)(aptr + k0 + BK);
                ap1 = *(const float4*)(aptr + k0 + BK + 4);
                ap2 = *(const float4*)(aptr + k0 + BK + 64);
                ap3 = *(const float4*)(aptr + k0 + BK + 68);
            }
#pragma unroll
            for (int i = 0; i < 2; ++i)
#pragma unroll
                for (int j = 0; j < 2; ++j) {
                    acc[i][j] = __builtin_amdgcn_mfma_f32_16x16x32_bf16(af[i][0], bfr[j][0], acc[i][j], 0, 0, 0);
                    acc[i][j] = __builtin_amdgcn_mfma_f32_16x16x32_bf16(af[i][1], bfr[j][1], acc[i][j], 0, 0, 0);
                }
        }
        __syncthreads();  // done reading As/Bs
        if (k0 + BK < V_) {
#pragma unroll
            for (int q = 0; q < 8; ++q)
                gload_lds16(bgsrc + (size_t)q * 16 * V_ + (k0 + BK), &Bs[(q * 16 + wv * 4) * BK]);
        }
    }
    // epilogue: bias + relu -> global + LDS tile. C/D: n = lane&15 (+16j),
    // m = lq*4 + reg (+16i)
#pragma unroll
    for (int j = 0; j < 2; ++j) {
        const int n = n0w + j * 16 + lm;
        const float bi = (n < 64) ? U1b[n] : U2b[n - 64];
#pragma unroll
        for (int i = 0; i < 2; ++i)
#pragma unroll
            for (int r = 0; r < 4; ++r) {
                const int ml = i * 16 + lq * 4 + r;
                const float val = fmaxf(acc[i][j][r] + bi, 0.f);
                Cs[ml][n] = val;
                LR[(size_t)(m0 + ml) * 128 + n] = val;
            }
    }
    __syncthreads();
    // d_m = sum_{k<64} right[m,k]*left[m,k]; 8 lanes per m, shuffle-reduce
    {
        const int m = t >> 3, ks = t & 7;
        float dd = 0.f;
#pragma unroll
        for (int u = 0; u < 8; ++u)
            dd += Cs[m][ks * 8 + u] * Cs[m][64 + ks * 8 + u];
        dd += __shfl_xor(dd, 1, 64);
        dd += __shfl_xor(dd, 2, 64);
        dd += __shfl_xor(dd, 4, 64);
        if (ks == 0) dvec[m0 + m] = rsqrtf(dd + 1e-6f);
    }
}

// ---------------- kernel 3: fused lbar/s + feats, 1024 threads -------------
// grid 256 = b(64) x vc(4) (8-way split regressed +17us, R3 — do not retry).
// d-phase REMOVED (R7): dvec precomputed by gemm_lr epilogue; prelude is now
// load dl (1KB) -> lbar -> s. 16 waves/CU for the Vmat-streaming feats phase.
__global__ __launch_bounds__(1024) void kfs(const float* __restrict__ LR,
                                            const float* __restrict__ Vmat,
                                            const float* __restrict__ dvec,
                                            float* __restrict__ F) {
    const int b = blockIdx.x >> 2, vc = blockIdx.x & 3;
    const float* Lb = LR + (size_t)b * N_ * 128;
    __shared__ float dl[256];
    __shared__ float kred[16][64];
    __shared__ float lbar[64];
    __shared__ float sl[256];
    __shared__ float4 part[1024];
    const int t = threadIdx.x;

    if (t < 256) dl[t] = dvec[b * N_ + t];
    __syncthreads();
    // lbar[k] = sum_n dl[n] * left[n][k]; 16 n-groups x 64 k
    {
        const int k = t & 63, g = t >> 6;
        float acc = 0.f;
        for (int n = g; n < N_; n += 16)
            acc += dl[n] * Lb[(size_t)n * 128 + 64 + k];
        kred[g][k] = acc;
    }
    __syncthreads();
    if (t < 64) {
        float v = 0.f;
#pragma unroll
        for (int g = 0; g < 16; ++g) v += kred[g][t];
        lbar[t] = v;
    }
    __syncthreads();
    // s[m] = ((N+1) - d_m * (lbar . right_m)) / N, t<256
    if (t < 256) {
        const float* row = Lb + (size_t)t * 128;
        float a2 = 0.f;
#pragma unroll 8
        for (int kk = 0; kk < 64; ++kk) a2 += lbar[kk] * row[kk];
        sl[t] = ((float)(N_ + 1) - dl[t] * a2) * (1.0f / (float)N_);
    }
    __syncthreads();
    // feats chunk: thread (v4 = t&127, mh = t>>7 in 0..7) covers 32 m-rows
    const int v4 = t & 127, mh = t >> 7;
    const int v = vc * 512 + v4 * 4;
    const float* base = Vmat + (size_t)b * N_ * V_ + (size_t)mh * 32 * V_ + v;
    float4 a = {0.f, 0.f, 0.f, 0.f};
#pragma unroll
    for (int m = 0; m < 32; m += 16) {
        float4 x[16];
#pragma unroll
        for (int u = 0; u < 16; ++u) x[u] = *(const float4*)(base + (size_t)(m + u) * V_);
#pragma unroll
        for (int u = 0; u < 16; ++u) {
            float sv = sl[mh * 32 + m + u];
            a.x += sv * x[u].x; a.y += sv * x[u].y;
            a.z += sv * x[u].z; a.w += sv * x[u].w;
        }
    }
    part[t] = a;
    __syncthreads();
    if (t < 128) {
        a = part[t];
#pragma unroll
        for (int g = 1; g < 8; ++g) {
            float4 p = part[t + g * 128];
            a.x += p.x; a.y += p.y; a.z += p.z; a.w += p.w;
        }
        F[(size_t)(v + 0) * 64 + b] = a.x;
        F[(size_t)(v + 1) * 64 + b] = a.y;
        F[(size_t)(v + 2) * 64 + b] = a.z;
        F[(size_t)(v + 3) * 64 + b] = a.w;
    }
}

// ---------------- kernel 4: fused linear + BatchNorm (512 thr, 8-way K) ---
// single F buffer (0.5MB L2/block). (b_lin dropped: cancels in BatchNorm)
__global__ __launch_bounds__(512) void klinbn(const float* __restrict__ F,
                                              const float* __restrict__ Wl,
                                              const float* __restrict__ gamma,
                                              const float* __restrict__ beta,
                                              float* __restrict__ out) {
    __shared__ float red[8][4][64];
    const int e0 = blockIdx.x * 4;
    const int t = threadIdx.x, b = t & 63, g = t >> 6;  // g: 0..7 k-slices
    const float* w0 = Wl + (size_t)(e0 + 0) * V_ + g * 256;
    const float* w1 = Wl + (size_t)(e0 + 1) * V_ + g * 256;
    const float* w2 = Wl + (size_t)(e0 + 2) * V_ + g * 256;
    const float* w3 = Wl + (size_t)(e0 + 3) * V_ + g * 256;
    const float* f0 = F + (size_t)g * 256 * 64 + b;
    float a0 = 0.f, a1 = 0.f, a2 = 0.f, a3 = 0.f;
#pragma unroll 4
    for (int k = 0; k < 256; ++k) {
        float fv = f0[(size_t)k * 64];
        a0 += fv * w0[k]; a1 += fv * w1[k]; a2 += fv * w2[k]; a3 += fv * w3[k];
    }
    red[g][0][b] = a0; red[g][1][b] = a1; red[g][2][b] = a2; red[g][3][b] = a3;
    __syncthreads();
    if (t < 256) {
        const int e = t >> 6;  // wave e owns e-row e0+e across lanes b
        float v = 0.f;
#pragma unroll
        for (int gg = 0; gg < 8; ++gg) v += red[gg][e][b];
        float sum = v;
#pragma unroll
        for (int o = 1; o < 64; o <<= 1) sum += __shfl_xor(sum, o, 64);
        float mu = sum * (1.f / 64.f);
        float dvv = v - mu;
        float q = dvv * dvv;
#pragma unroll
        for (int o = 1; o < 64; o <<= 1) q += __shfl_xor(q, o, 64);
        float inv = rsqrtf(q * (1.f / 64.f) + 1e-5f);
        red[0][e][b] = gamma[e0 + e] * dvv * inv + beta[e0 + e];
    }
    __syncthreads();
    if (t < 256) {
        const int b2 = t >> 2, j = t & 3;
        out[(size_t)b2 * E_ + e0 + j] = red[0][j][b2];
    }
}

extern "C" void kernel_launch(void* const* d_in, const int* in_sizes, int n_in,
                              void* d_out, int out_size, void* d_ws, size_t ws_size,
                              hipStream_t stream) {
    const float* Vmat = (const float*)d_in[0];
    const float* U1v  = (const float*)d_in[1];
    const float* U1g  = (const float*)d_in[2];
    const float* U1b  = (const float*)d_in[3];
    const float* U2v  = (const float*)d_in[4];
    const float* U2g  = (const float*)d_in[5];
    const float* U2b  = (const float*)d_in[6];
    const float* Wl   = (const float*)d_in[7];
    // d_in[8] = b_lin: unused (cancels in BatchNorm)
    const float* gam  = (const float*)d_in[9];
    const float* bet  = (const float*)d_in[10];

    float*  ws     = (float*)d_ws;
    float*  dvec   = ws + OFF_S;
    float*  LR     = ws + OFF_LR;
    float*  F      = ws + OFF_FT;
    bf16_t* Wb     = (bf16_t*)(ws + OFF_WB);

    kprep  <<<128, 256, 0, stream>>>(U1v, U1g, U2v, U2g, Wb);
    gemm_lr<<<MROWS / 32, 256, 0, stream>>>(Vmat, Wb, U1b, U2b, LR, dvec);
    kfs    <<<B_ * 4, 1024, 0, stream>>>(LR, Vmat, dvec, F);
    klinbn <<<E_ / 4, 512, 0, stream>>>(F, Wl, gam, bet, (float*)d_out);
}